// Round 10
// baseline (430.989 us; speedup 1.0000x reference)
//
#include <hip/hip_runtime.h>
#include <cmath>

// ---------------------------------------------------------------------------
// T5-style attention, B=4 S=2048 H=16 dk=64, D_MODEL=1024, buckets=32.
// Outputs: out [4,2048,1024] f32, then masks [4,16,2048,2048] f32.
// Fused path: attn computes m = pb + am per tile, stores masks (nontemporal
// f32x4 full lines) overlapped with MFMA; softmax overwrites m with P in
// place so ms/Pl/Qs share one buffer. K/V staged via global_load_lds with
// pre-swizzled source (GEMM pattern) -> async, register-neutral, 39 KB LDS,
// 3 blocks/CU. GEMM epilogues repack C through swizzled LDS (16B stores,
// incl. V-transpose [b,h,d,j] and the f32 O-projection).
// ---------------------------------------------------------------------------

typedef __attribute__((ext_vector_type(8))) short bf16x8;
typedef __attribute__((ext_vector_type(4))) float f32x4;
typedef __attribute__((ext_vector_type(8))) unsigned short u16x8;

#define MFMA16(a, b, c) __builtin_amdgcn_mfma_f32_16x16x32_bf16((a), (b), (c), 0, 0, 0)

#define ASYNC_COPY16(g, l)                                                              \
  __builtin_amdgcn_global_load_lds((const __attribute__((address_space(1))) void*)(g),  \
                                   (__attribute__((address_space(3))) void*)(l), 16, 0, 0)

__device__ __forceinline__ unsigned short f2bf(float f) {
  unsigned u = __float_as_uint(f);
  u += 0x7FFFu + ((u >> 16) & 1u);   // round-to-nearest-even
  return (unsigned short)(u >> 16);
}
__device__ __forceinline__ float bf2f(unsigned short u) {
  return __uint_as_float(((unsigned)u) << 16);
}

// Exact integer-threshold version of the T5 bidirectional bucket.
__device__ __forceinline__ int t5_bucket(int rel) {
  int bkt = (rel > 0) ? 16 : 0;
  int d = (rel < 0) ? -rel : rel;
  int v;
  if (d < 8) v = d;
  else if (d < 12) v = 8;
  else if (d < 16) v = 9;
  else if (d < 23) v = 10;
  else if (d < 32) v = 11;
  else if (d < 46) v = 12;
  else if (d < 64) v = 13;
  else if (d < 91) v = 14;
  else v = 15;
  return bkt + v;
}

// ----------------- fused f32 -> bf16 cast over 5 segments ------------------
struct Cast5Args {
  const float* src[5];
  unsigned short* dst[5];
};
__global__ __launch_bounds__(256) void cast5_kernel(Cast5Args a) {
  int i = (blockIdx.x * 256 + threadIdx.x) * 4;
  int seg, loc;
  if (i < 8388608) { seg = 0; loc = i; }
  else { seg = 1 + ((i - 8388608) >> 20); loc = (i - 8388608) & 1048575; }
  float4 v = *(const float4*)(a.src[seg] + loc);
  ushort4 o;
  o.x = f2bf(v.x); o.y = f2bf(v.y); o.z = f2bf(v.z); o.w = f2bf(v.w);
  *(ushort4*)(a.dst[seg] + loc) = o;
}

// ------------------- GEMM core (C = A * B^T + bias) ------------------------
// 128x128 tile, BK=64, 4 waves (2x2), 16x16x32 MFMA, global_load_lds w=16
// with pre-swizzled global source (LDS row = 8 x 16B units, unit^(row&7)).
// sh is 2*128*64 shorts (32 KB); reused as the epilogue repack buffer.
// epi: 0 = f32 out (LDS repack, two passes), 1 = bf16 out (LDS repack),
//      2 = bf16 transposed (LDS repack, V: [b,h,d,j] layout).
__device__ __forceinline__ void gemm_core(const unsigned short* __restrict__ A,
                                          const unsigned short* __restrict__ Bt,
                                          const float* __restrict__ bias,
                                          void* __restrict__ Cout, int M, int N, int K,
                                          int epi, short* sh) {
  short* As = sh;
  short* Bs = sh + 128 * 64;
  const int lane = threadIdx.x & 63;
  const int wave = threadIdx.x >> 6;
  const int l15 = lane & 15, g = lane >> 4;
  const int m0 = blockIdx.x * 128;
  const int n0 = blockIdx.y * 128;
  const int wr = wave >> 1, wc = wave & 1;

  f32x4 acc[4][4] = {};

  const int srow_in = lane >> 3;
  const int spu = lane & 7;

  for (int k0 = 0; k0 < K; k0 += 64) {
#pragma unroll
    for (int q = 0; q < 4; ++q) {
      const int rbase = (wave * 4 + q) * 8;
      const int row = rbase + srow_in;
      const int usrc = spu ^ (row & 7);
      ASYNC_COPY16(A + (size_t)(m0 + row) * K + k0 + usrc * 8, As + rbase * 64);
      ASYNC_COPY16(Bt + (size_t)(n0 + row) * K + k0 + usrc * 8, Bs + rbase * 64);
    }
    __syncthreads();

#pragma unroll
    for (int kk = 0; kk < 2; ++kk) {
      bf16x8 af[4], bfr[4];
#pragma unroll
      for (int mi = 0; mi < 4; ++mi) {
        int row = wr * 64 + mi * 16 + l15;
        int pu = (kk * 4 + g) ^ (row & 7);
        af[mi] = *(const bf16x8*)(As + row * 64 + pu * 8);
      }
#pragma unroll
      for (int ni = 0; ni < 4; ++ni) {
        int row = wc * 64 + ni * 16 + l15;
        int pu = (kk * 4 + g) ^ (row & 7);
        bfr[ni] = *(const bf16x8*)(Bs + row * 64 + pu * 8);
      }
#pragma unroll
      for (int mi = 0; mi < 4; ++mi)
#pragma unroll
        for (int ni = 0; ni < 4; ++ni)
          acc[mi][ni] = MFMA16(af[mi], bfr[ni], acc[mi][ni]);
    }
    __syncthreads();   // also: As/Bs free for epilogue reuse after last iter
  }

  float bvv[4];
#pragma unroll
  for (int ni = 0; ni < 4; ++ni) bvv[ni] = bias[n0 + wc * 64 + ni * 16 + l15];

  if (epi == 0) {
    // f32 out via two-pass LDS repack: pass p handles rows [p*64, p*64+64).
    // sh as f32 [64][128], unit (16B) swizzle pu = cu ^ (m&7).
    float* shf = (float*)sh;
#pragma unroll
    for (int p = 0; p < 2; ++p) {
      if (p) __syncthreads();
      if (wr == p) {
#pragma unroll
        for (int mi = 0; mi < 4; ++mi) {
#pragma unroll
          for (int ni = 0; ni < 4; ++ni) {
            int c = wc * 64 + ni * 16 + l15;
#pragma unroll
            for (int r = 0; r < 4; ++r) {
              int m = mi * 16 + (g << 2) + r;
              shf[m * 128 + ((((c >> 2) ^ (m & 7)) << 2) | (c & 3))] =
                  acc[mi][ni][r] + bvv[ni];
            }
          }
        }
      }
      __syncthreads();
      {
        int row = threadIdx.x >> 5;          // 0..7
        int u = threadIdx.x & 31;            // 16B unit within row
#pragma unroll
        for (int k = 0; k < 8; ++k) {
          int rr = row + (k << 3);           // 0..63
          int pu = u ^ (rr & 7);
          f32x4 v = *(const f32x4*)(shf + rr * 128 + (pu << 2));
          *(f32x4*)((float*)Cout + (size_t)(m0 + p * 64 + rr) * N + n0 + (u << 2)) = v;
        }
      }
    }
  } else if (epi == 1) {
    // bf16 row-major via LDS repack: sh[m][128 cols], phys unit = u^(m&7)
#pragma unroll
    for (int mi = 0; mi < 4; ++mi) {
      int ml = wr * 64 + mi * 16 + (g << 2);
#pragma unroll
      for (int ni = 0; ni < 4; ++ni) {
        int c = wc * 64 + ni * 16 + l15;
#pragma unroll
        for (int r = 0; r < 4; ++r) {
          int m = ml + r;
          int pc = (((c >> 3) ^ (m & 7)) << 3) | (c & 7);
          sh[m * 128 + pc] = (short)f2bf(acc[mi][ni][r] + bvv[ni]);
        }
      }
    }
    __syncthreads();
    {
      int m = threadIdx.x >> 1, half = threadIdx.x & 1;
      unsigned short* dst = (unsigned short*)Cout + (size_t)(m0 + m) * N + n0 + half * 64;
#pragma unroll
      for (int uu = 0; uu < 8; ++uu) {
        int u = half * 8 + uu;
        int pu = u ^ (m & 7);
        *(u16x8*)(dst + uu * 8) = *(const u16x8*)(sh + m * 128 + pu * 8);
      }
    }
  } else {
    // bf16 transposed via LDS repack: sh[c][128 m], phys unit = u^(c&7)
#pragma unroll
    for (int mi = 0; mi < 4; ++mi) {
      int ml = wr * 64 + mi * 16 + (g << 2);
#pragma unroll
      for (int ni = 0; ni < 4; ++ni) {
        int c = wc * 64 + ni * 16 + l15;
#pragma unroll
        for (int r = 0; r < 4; ++r) {
          int s = ml + r;
          int ps = (((s >> 3) ^ (c & 7)) << 3) | (s & 7);
          sh[c * 128 + ps] = (short)f2bf(acc[mi][ni][r] + bvv[ni]);
        }
      }
    }
    __syncthreads();
    {
      int c = threadIdx.x >> 1, half = threadIdx.x & 1;
      int col = n0 + c;                       // col = h*64 + d
      int mb = m0 >> 11, ml = m0 & 2047;      // batch / token-within-batch
      unsigned short* dst =
          (unsigned short*)Cout + (((size_t)(mb * 1024 + col)) << 11) + ml + half * 64;
#pragma unroll
      for (int uu = 0; uu < 8; ++uu) {
        int u = half * 8 + uu;
        int pu = u ^ (c & 7);
        *(u16x8*)(dst + uu * 8) = *(const u16x8*)(sh + c * 128 + pu * 8);
      }
    }
  }
}

struct QKVArgs {
  const unsigned short* A;
  const unsigned short* Bt[3];
  const float* bias[3];
  unsigned short* out[3];
};
__global__ __launch_bounds__(256) void qkv_gemm(QKVArgs a) {
  __shared__ __align__(16) short sh[2 * 128 * 64];
  const int z = blockIdx.z;
  gemm_core(a.A, a.Bt[z], a.bias[z], a.out[z], 8192, 1024, 1024, z == 2 ? 2 : 1, sh);
}

__global__ __launch_bounds__(256) void gemm_f32(const unsigned short* A,
                                                const unsigned short* Bt, const float* bias,
                                                float* Cout) {
  __shared__ __align__(16) short sh[2 * 128 * 64];
  gemm_core(A, Bt, bias, Cout, 8192, 1024, 1024, 0, sh);
}

// ------------------------- fused attention ---------------------------------
// Per block: (b,h), 128 Q-rows, 8 waves. No-max softmax (|logit| < ~0.02).
// Per k-tile: K/V staged via global_load_lds (pre-swizzled source, linear
// [64][64] LDS, XOR'd fragment reads) issued first so they fly under the am
// staging; m = pb + am -> msPl (bf16) + nontemporal masks stores. Softmax
// overwrites m with P IN PLACE (same lane, same slot), so msPl also serves
// as P staging (and as Qs pre-loop). Row sums via ones-column MFMA.
// LDS 39168 B -> 3 blocks/CU.
template <int WM>
__global__ __launch_bounds__(512) void attn_fused(const unsigned short* __restrict__ Qg,
                                                  const unsigned short* __restrict__ Kg,
                                                  const unsigned short* __restrict__ Vtg,
                                                  const float* __restrict__ am,
                                                  const float* __restrict__ rel_emb,
                                                  unsigned short* __restrict__ Og,
                                                  float* __restrict__ mout) {
  const int bh = blockIdx.x;           // XCD-affine: all q-tiles of bh on xcd bh%8
  const int b = bh >> 4, h = bh & 15;
  const int q0 = blockIdx.y << 7;
  const int tid = threadIdx.x;
  const int lane = tid & 63, wave = tid >> 6;
  const int l15 = lane & 15, g = lane >> 4;

  __shared__ __align__(16) short Ks[64 * 64];          // linear, swizzled units
  __shared__ __align__(16) short Vt[64 * 64];          // Vt[d][j], linear
  __shared__ unsigned short pbr[2176];                 // bf16 pb, block-local
  __shared__ __align__(16) unsigned short msPl[128 * 72];  // m-tile == P == Qs
  short* Qs = (short*)msPl;

  // pbr[t] = rel_emb[bucket(t - 127 - q0)][h]; idx = j - row_local + 127
  for (int t = tid; t < 2176; t += 512)
    pbr[t] = f2bf(rel_emb[t5_bucket(t - 127 - q0) * 16 + h]);

  const size_t base = ((size_t)b * 2048) * 1024 + h * 64;   // Q/K/O token-major
  const size_t vtbase = (size_t)bh << 17;                   // Vt [bh][64][2048]

  {  // stage Q tile [128][64] -> Qs (aliases msPl; consumed before kt loop)
    int row = tid >> 2, cu = (tid & 3) << 4;
    const unsigned short* src = Qg + base + (size_t)(q0 + row) * 1024 + cu;
    u16x8 v0 = *(const u16x8*)src;
    u16x8 v1 = *(const u16x8*)(src + 8);
    *(u16x8*)(Qs + row * 72 + cu) = v0;
    *(u16x8*)(Qs + row * 72 + cu + 8) = v1;
  }
  __syncthreads();

  bf16x8 qf[2];
  {
    int row = (wave << 4) + l15;
    const short* p = Qs + row * 72 + (g << 3);
    qf[0] = *(const bf16x8*)p;
    qf[1] = *(const bf16x8*)(p + 32);
  }

  f32x4 acc[4] = {};
  f32x4 acc1 = {};                               // P row sums (ones-column)
  const bf16x8 onesf = {16256, 16256, 16256, 16256, 16256, 16256, 16256, 16256};
  const int ilbase = (wave << 4) + (g << 2);     // local q-row for r=0
  const float SC = 1.442695041f / 4096.0f;

  // K/V async staging geometry (GEMM pattern): wave w fills rows [8w, 8w+8)
  const int krow = (wave << 3) + (lane >> 3);    // j-row (K) / d-row (V)
  const int ausrc = (lane & 7) ^ (krow & 7);     // pre-swizzled source unit
  const unsigned short* kptr = Kg + base + (size_t)krow * 1024 + ausrc * 8;
  const unsigned short* vptr = Vtg + vtbase + ((size_t)krow << 11) + ausrc * 8;
  short* kdst = Ks + (wave << 3) * 64;           // wave-uniform LDS dest
  short* vdst = Vt + (wave << 3) * 64;

  const int mrow = tid >> 4;                     // am staging: 32-row passes
  const int mf4 = tid & 15;                      // float4 index (256B lines)

  for (int kt = 0; kt < 32; ++kt) {
    const int j0 = kt << 6;
    __syncthreads();  // prev readers of Ks/Vt/msPl done; prev stores drained
    // issue async K/V -> LDS first; they complete under the am staging
    ASYNC_COPY16(kptr + (size_t)j0 * 1024, kdst);
    ASYNC_COPY16(vptr + j0, vdst);
    // stage m = pb + am tile (float4 loads, 256B contiguous per 16 lanes)
    f32x4 mreg[4];
#pragma unroll
    for (int p = 0; p < 4; ++p) {
      const int row = p * 32 + mrow;
      const int j = j0 + (mf4 << 2);
      f32x4 a = *(const f32x4*)(am + ((size_t)b * 2048 + q0 + row) * 2048 + j);
      const int pidx = j - row + 127;
      f32x4 m;
      m[0] = bf2f(pbr[pidx + 0]) + a[0];
      m[1] = bf2f(pbr[pidx + 1]) + a[1];
      m[2] = bf2f(pbr[pidx + 2]) + a[2];
      m[3] = bf2f(pbr[pidx + 3]) + a[3];
      mreg[p] = m;
      ushort4 mb;
      mb.x = f2bf(m[0]); mb.y = f2bf(m[1]); mb.z = f2bf(m[2]); mb.w = f2bf(m[3]);
      *(ushort4*)(msPl + row * 72 + (mf4 << 2)) = mb;
    }
    __syncthreads();  // K/V async copies + msPl writes complete

    if (WM) {  // nontemporal masks stores; drain overlaps the compute phase
#pragma unroll
      for (int p = 0; p < 4; ++p) {
        const int row = p * 32 + mrow;
        f32x4* dst =
            (f32x4*)(mout + ((size_t)bh * 2048 + q0 + row) * 2048 + j0 + (mf4 << 2));
        __builtin_nontemporal_store(mreg[p], dst);
      }
    }

    // S = Q K^T
    f32x4 sacc[4] = {};
#pragma unroll
    for (int kk = 0; kk < 2; ++kk) {
#pragma unroll
      for (int fj = 0; fj < 4; ++fj) {
        int row = (fj << 4) + l15;
        int pu = (kk * 4 + g) ^ (row & 7);
        bf16x8 kf = *(const bf16x8*)(Ks + row * 64 + pu * 8);
        sacc[fj] = MFMA16(qf[kk], kf, sacc[fj]);
      }
    }

    // P = exp2((s + m) * SC); overwrite m with P in place (same lane+slot)
#pragma unroll
    for (int fj = 0; fj < 4; ++fj) {
      const int jl = (fj << 4) + l15;
#pragma unroll
      for (int r = 0; r < 4; ++r) {
        const int il = (wave << 4) + (g << 2) + r;
        float mval = bf2f(msPl[il * 72 + jl]);
        float p = exp2f((sacc[fj][r] + mval) * SC);
        msPl[il * 72 + jl] = f2bf(p);
      }
    }
    // msPl rows of this wave are wave-private: in-order LDS, no barrier.

    // O += P V ; row sums += P * ones (matrix pipe)
#pragma unroll
    for (int kk = 0; kk < 2; ++kk) {
      const int koff = (kk << 5) + (g << 3);
      bf16x8 pf = *(const bf16x8*)((const short*)msPl + ((wave << 4) + l15) * 72 + koff);
      acc1 = MFMA16(pf, onesf, acc1);
#pragma unroll
      for (int fd = 0; fd < 4; ++fd) {
        int row = (fd << 4) + l15;
        int pu = (kk * 4 + g) ^ (row & 7);
        bf16x8 vf = *(const bf16x8*)(Vt + row * 64 + pu * 8);
        acc[fd] = MFMA16(pf, vf, acc[fd]);
      }
    }
  }

#pragma unroll
  for (int fd = 0; fd < 4; ++fd) {
    int d = (fd << 4) + l15;
#pragma unroll
    for (int r = 0; r < 4; ++r) {
      float o = acc[fd][r] / acc1[r];
      Og[base + (size_t)(q0 + ilbase + r) * 1024 + d] = f2bf(o);
    }
  }
}

// ---------------------------- masks output (fallback path) -----------------
__global__ __launch_bounds__(256) void masks_kernel(const float* __restrict__ am,
                                                    const float* __restrict__ rel_emb,
                                                    float* __restrict__ mout) {
  const int bi = blockIdx.x;
  const int b = bi >> 11, i = bi & 2047;
  __shared__ float amrow[2048];
  __shared__ float remb[512];
  __shared__ unsigned char bkt[2048];
  for (int t = threadIdx.x; t < 512; t += 256) remb[t] = rel_emb[t];
  const float* arow = am + ((size_t)b * 2048 + i) * 2048;
  for (int t = threadIdx.x; t < 512; t += 256)
    *(float4*)(amrow + (t << 2)) = *(const float4*)(arow + (t << 2));
  for (int j = threadIdx.x; j < 2048; j += 256)
    bkt[j] = (unsigned char)t5_bucket(j - i);
  __syncthreads();
  for (int h = 0; h < 16; ++h) {
    float* dst = mout + (((size_t)(b * 16 + h)) * 2048 + i) * 2048;
    for (int t = threadIdx.x; t < 512; t += 256) {
      int j = t << 2;
      f32x4 o;
      o[0] = remb[(bkt[j + 0] << 4) + h] + amrow[j + 0];
      o[1] = remb[(bkt[j + 1] << 4) + h] + amrow[j + 1];
      o[2] = remb[(bkt[j + 2] << 4) + h] + amrow[j + 2];
      o[3] = remb[(bkt[j + 3] << 4) + h] + amrow[j + 3];
      __builtin_nontemporal_store(o, (f32x4*)(dst + j));
    }
  }
}

// ---------------------------------------------------------------------------
extern "C" void kernel_launch(void* const* d_in, const int* in_sizes, int n_in,
                              void* d_out, int out_size, void* d_ws, size_t ws_size,
                              hipStream_t stream) {
  const float* hs  = (const float*)d_in[0];
  const float* am  = (const float*)d_in[1];
  const float* Wq  = (const float*)d_in[2];
  const float* bq  = (const float*)d_in[3];
  const float* Wk  = (const float*)d_in[4];
  const float* bk  = (const float*)d_in[5];
  const float* Wv  = (const float*)d_in[6];
  const float* bv  = (const float*)d_in[7];
  const float* Wo  = (const float*)d_in[8];
  const float* bo  = (const float*)d_in[9];
  const float* rel = (const float*)d_in[10];

  float* out = (float*)d_out;
  float* mout = out + (size_t)8388608;           // masks region (1.07 GB)

  const bool fused = ws_size >= (size_t)69206016;

  unsigned short *hsb, *wqb, *wkb, *wvb, *wob, *qb, *kb, *vtb, *aob;
  if (fused) {
    char* W = (char*)d_ws;
    qb  = (unsigned short*)(W);
    kb  = (unsigned short*)(W + 16777216);
    vtb = (unsigned short*)(W + 33554432);
    aob = (unsigned short*)(W + 50331648);
    wob = (unsigned short*)(W + 67108864);
    char* SB = (char*)mout;
    hsb = (unsigned short*)(SB);
    wqb = (unsigned short*)(SB + 16777216);
    wkb = (unsigned short*)(SB + 18874368);
    wvb = (unsigned short*)(SB + 20971520);
  } else {
    char* SB = (char*)mout;
    hsb = (unsigned short*)(SB);
    wqb = (unsigned short*)(SB + 16777216);
    wkb = (unsigned short*)(SB + 18874368);
    wvb = (unsigned short*)(SB + 20971520);
    wob = (unsigned short*)(SB + 23068672);
    qb  = (unsigned short*)(SB + 25165824);
    kb  = (unsigned short*)(SB + 41943040);
    vtb = (unsigned short*)(SB + 58720256);
    aob = (unsigned short*)(SB + 75497472);
  }

  Cast5Args ca;
  ca.src[0] = hs;  ca.dst[0] = hsb;
  ca.src[1] = Wq;  ca.dst[1] = wqb;
  ca.src[2] = Wk;  ca.dst[2] = wkb;
  ca.src[3] = Wv;  ca.dst[3] = wvb;
  ca.src[4] = Wo;  ca.dst[4] = wob;
  cast5_kernel<<<12288, 256, 0, stream>>>(ca);

  QKVArgs qa;
  qa.A = hsb;
  qa.Bt[0] = wqb;  qa.bias[0] = bq;  qa.out[0] = qb;
  qa.Bt[1] = wkb;  qa.bias[1] = bk;  qa.out[1] = kb;
  qa.Bt[2] = wvb;  qa.bias[2] = bv;  qa.out[2] = vtb;
  qkv_gemm<<<dim3(64, 8, 3), 256, 0, stream>>>(qa);

  if (fused) {
    attn_fused<1><<<dim3(64, 16), 512, 0, stream>>>(qb, kb, vtb, am, rel, aob, mout);
  } else {
    attn_fused<0><<<dim3(64, 16), 512, 0, stream>>>(qb, kb, vtb, am, rel, aob, mout);
  }

  gemm_f32<<<dim3(64, 8), 256, 0, stream>>>(aob, wob, bo, out);

  if (!fused) masks_kernel<<<8192, 256, 0, stream>>>(am, rel, mout);
}

// Round 11
// 403.439 us; speedup vs baseline: 1.0683x; 1.0683x over previous
//
#include <hip/hip_runtime.h>
#include <cmath>

// ---------------------------------------------------------------------------
// T5-style attention, B=4 S=2048 H=16 dk=64, D_MODEL=1024, buckets=32.
// Outputs: out [4,2048,1024] f32, then masks [4,16,2048,2048] f32.
// Fused path: attn computes m = pb + am per tile, stores masks (nontemporal
// f32x4 full lines) overlapped with MFMA; softmax overwrites m with P in
// place so ms/Pl/Qs share one 41 KB buffer -> 3 blocks/CU. Attn K/V staging
// is the round-9 reg-staged padded-72 form (r10's global_load_lds variant
// regressed -21us: XOR addr math on the MFMA read path, no overlap gain).
// GEMM epilogues repack C through swizzled LDS (16B stores, incl.
// V-transpose [b,h,d,j] and the f32 O-projection).
// ---------------------------------------------------------------------------

typedef __attribute__((ext_vector_type(8))) short bf16x8;
typedef __attribute__((ext_vector_type(4))) float f32x4;
typedef __attribute__((ext_vector_type(8))) unsigned short u16x8;

#define MFMA16(a, b, c) __builtin_amdgcn_mfma_f32_16x16x32_bf16((a), (b), (c), 0, 0, 0)

#define ASYNC_COPY16(g, l)                                                              \
  __builtin_amdgcn_global_load_lds((const __attribute__((address_space(1))) void*)(g),  \
                                   (__attribute__((address_space(3))) void*)(l), 16, 0, 0)

__device__ __forceinline__ unsigned short f2bf(float f) {
  unsigned u = __float_as_uint(f);
  u += 0x7FFFu + ((u >> 16) & 1u);   // round-to-nearest-even
  return (unsigned short)(u >> 16);
}
__device__ __forceinline__ float bf2f(unsigned short u) {
  return __uint_as_float(((unsigned)u) << 16);
}

// Exact integer-threshold version of the T5 bidirectional bucket.
__device__ __forceinline__ int t5_bucket(int rel) {
  int bkt = (rel > 0) ? 16 : 0;
  int d = (rel < 0) ? -rel : rel;
  int v;
  if (d < 8) v = d;
  else if (d < 12) v = 8;
  else if (d < 16) v = 9;
  else if (d < 23) v = 10;
  else if (d < 32) v = 11;
  else if (d < 46) v = 12;
  else if (d < 64) v = 13;
  else if (d < 91) v = 14;
  else v = 15;
  return bkt + v;
}

// ----------------- fused f32 -> bf16 cast over 5 segments ------------------
struct Cast5Args {
  const float* src[5];
  unsigned short* dst[5];
};
__global__ __launch_bounds__(256) void cast5_kernel(Cast5Args a) {
  int i = (blockIdx.x * 256 + threadIdx.x) * 4;
  int seg, loc;
  if (i < 8388608) { seg = 0; loc = i; }
  else { seg = 1 + ((i - 8388608) >> 20); loc = (i - 8388608) & 1048575; }
  float4 v = *(const float4*)(a.src[seg] + loc);
  ushort4 o;
  o.x = f2bf(v.x); o.y = f2bf(v.y); o.z = f2bf(v.z); o.w = f2bf(v.w);
  *(ushort4*)(a.dst[seg] + loc) = o;
}

// ------------------- GEMM core (C = A * B^T + bias) ------------------------
// 128x128 tile, BK=64, 4 waves (2x2), 16x16x32 MFMA, global_load_lds w=16
// with pre-swizzled global source (LDS row = 8 x 16B units, unit^(row&7)).
// sh is 2*128*64 shorts (32 KB); reused as the epilogue repack buffer.
// epi: 0 = f32 out (LDS repack, two passes), 1 = bf16 out (LDS repack),
//      2 = bf16 transposed (LDS repack, V: [b,h,d,j] layout).
__device__ __forceinline__ void gemm_core(const unsigned short* __restrict__ A,
                                          const unsigned short* __restrict__ Bt,
                                          const float* __restrict__ bias,
                                          void* __restrict__ Cout, int M, int N, int K,
                                          int epi, short* sh) {
  short* As = sh;
  short* Bs = sh + 128 * 64;
  const int lane = threadIdx.x & 63;
  const int wave = threadIdx.x >> 6;
  const int l15 = lane & 15, g = lane >> 4;
  const int m0 = blockIdx.x * 128;
  const int n0 = blockIdx.y * 128;
  const int wr = wave >> 1, wc = wave & 1;

  f32x4 acc[4][4] = {};

  const int srow_in = lane >> 3;
  const int spu = lane & 7;

  for (int k0 = 0; k0 < K; k0 += 64) {
#pragma unroll
    for (int q = 0; q < 4; ++q) {
      const int rbase = (wave * 4 + q) * 8;
      const int row = rbase + srow_in;
      const int usrc = spu ^ (row & 7);
      ASYNC_COPY16(A + (size_t)(m0 + row) * K + k0 + usrc * 8, As + rbase * 64);
      ASYNC_COPY16(Bt + (size_t)(n0 + row) * K + k0 + usrc * 8, Bs + rbase * 64);
    }
    __syncthreads();

#pragma unroll
    for (int kk = 0; kk < 2; ++kk) {
      bf16x8 af[4], bfr[4];
#pragma unroll
      for (int mi = 0; mi < 4; ++mi) {
        int row = wr * 64 + mi * 16 + l15;
        int pu = (kk * 4 + g) ^ (row & 7);
        af[mi] = *(const bf16x8*)(As + row * 64 + pu * 8);
      }
#pragma unroll
      for (int ni = 0; ni < 4; ++ni) {
        int row = wc * 64 + ni * 16 + l15;
        int pu = (kk * 4 + g) ^ (row & 7);
        bfr[ni] = *(const bf16x8*)(Bs + row * 64 + pu * 8);
      }
#pragma unroll
      for (int mi = 0; mi < 4; ++mi)
#pragma unroll
        for (int ni = 0; ni < 4; ++ni)
          acc[mi][ni] = MFMA16(af[mi], bfr[ni], acc[mi][ni]);
    }
    __syncthreads();   // also: As/Bs free for epilogue reuse after last iter
  }

  float bvv[4];
#pragma unroll
  for (int ni = 0; ni < 4; ++ni) bvv[ni] = bias[n0 + wc * 64 + ni * 16 + l15];

  if (epi == 0) {
    // f32 out via two-pass LDS repack: pass p handles rows [p*64, p*64+64).
    // sh as f32 [64][128], unit (16B) swizzle pu = cu ^ (m&7).
    float* shf = (float*)sh;
#pragma unroll
    for (int p = 0; p < 2; ++p) {
      if (p) __syncthreads();
      if (wr == p) {
#pragma unroll
        for (int mi = 0; mi < 4; ++mi) {
#pragma unroll
          for (int ni = 0; ni < 4; ++ni) {
            int c = wc * 64 + ni * 16 + l15;
#pragma unroll
            for (int r = 0; r < 4; ++r) {
              int m = mi * 16 + (g << 2) + r;
              shf[m * 128 + ((((c >> 2) ^ (m & 7)) << 2) | (c & 3))] =
                  acc[mi][ni][r] + bvv[ni];
            }
          }
        }
      }
      __syncthreads();
      {
        int row = threadIdx.x >> 5;          // 0..7
        int u = threadIdx.x & 31;            // 16B unit within row
#pragma unroll
        for (int k = 0; k < 8; ++k) {
          int rr = row + (k << 3);           // 0..63
          int pu = u ^ (rr & 7);
          f32x4 v = *(const f32x4*)(shf + rr * 128 + (pu << 2));
          *(f32x4*)((float*)Cout + (size_t)(m0 + p * 64 + rr) * N + n0 + (u << 2)) = v;
        }
      }
    }
  } else if (epi == 1) {
    // bf16 row-major via LDS repack: sh[m][128 cols], phys unit = u^(m&7)
#pragma unroll
    for (int mi = 0; mi < 4; ++mi) {
      int ml = wr * 64 + mi * 16 + (g << 2);
#pragma unroll
      for (int ni = 0; ni < 4; ++ni) {
        int c = wc * 64 + ni * 16 + l15;
#pragma unroll
        for (int r = 0; r < 4; ++r) {
          int m = ml + r;
          int pc = (((c >> 3) ^ (m & 7)) << 3) | (c & 7);
          sh[m * 128 + pc] = (short)f2bf(acc[mi][ni][r] + bvv[ni]);
        }
      }
    }
    __syncthreads();
    {
      int m = threadIdx.x >> 1, half = threadIdx.x & 1;
      unsigned short* dst = (unsigned short*)Cout + (size_t)(m0 + m) * N + n0 + half * 64;
#pragma unroll
      for (int uu = 0; uu < 8; ++uu) {
        int u = half * 8 + uu;
        int pu = u ^ (m & 7);
        *(u16x8*)(dst + uu * 8) = *(const u16x8*)(sh + m * 128 + pu * 8);
      }
    }
  } else {
    // bf16 transposed via LDS repack: sh[c][128 m], phys unit = u^(c&7)
#pragma unroll
    for (int mi = 0; mi < 4; ++mi) {
      int ml = wr * 64 + mi * 16 + (g << 2);
#pragma unroll
      for (int ni = 0; ni < 4; ++ni) {
        int c = wc * 64 + ni * 16 + l15;
#pragma unroll
        for (int r = 0; r < 4; ++r) {
          int s = ml + r;
          int ps = (((s >> 3) ^ (c & 7)) << 3) | (s & 7);
          sh[c * 128 + ps] = (short)f2bf(acc[mi][ni][r] + bvv[ni]);
        }
      }
    }
    __syncthreads();
    {
      int c = threadIdx.x >> 1, half = threadIdx.x & 1;
      int col = n0 + c;                       // col = h*64 + d
      int mb = m0 >> 11, ml = m0 & 2047;      // batch / token-within-batch
      unsigned short* dst =
          (unsigned short*)Cout + (((size_t)(mb * 1024 + col)) << 11) + ml + half * 64;
#pragma unroll
      for (int uu = 0; uu < 8; ++uu) {
        int u = half * 8 + uu;
        int pu = u ^ (c & 7);
        *(u16x8*)(dst + uu * 8) = *(const u16x8*)(sh + c * 128 + pu * 8);
      }
    }
  }
}

struct QKVArgs {
  const unsigned short* A;
  const unsigned short* Bt[3];
  const float* bias[3];
  unsigned short* out[3];
};
__global__ __launch_bounds__(256) void qkv_gemm(QKVArgs a) {
  __shared__ __align__(16) short sh[2 * 128 * 64];
  const int z = blockIdx.z;
  gemm_core(a.A, a.Bt[z], a.bias[z], a.out[z], 8192, 1024, 1024, z == 2 ? 2 : 1, sh);
}

__global__ __launch_bounds__(256) void gemm_f32(const unsigned short* A,
                                                const unsigned short* Bt, const float* bias,
                                                float* Cout) {
  __shared__ __align__(16) short sh[2 * 128 * 64];
  gemm_core(A, Bt, bias, Cout, 8192, 1024, 1024, 0, sh);
}

// ------------------------- fused attention ---------------------------------
// Round-9 verbatim (410 us, best known). Per block: (b,h), 128 Q-rows, 8
// waves. No-max softmax. Per k-tile: stage K/V (64x64 bf16, reg-staged into
// padded-72 LDS) + am (128x64 f32) -> m = pb + am -> msPl (bf16) +
// nontemporal masks stores. Softmax overwrites m with P IN PLACE, so msPl
// also serves as P staging (and as Qs pre-loop). Row sums via ones-column
// MFMA. LDS 41216 B -> 3 blocks/CU.
template <int WM>
__global__ __launch_bounds__(512) void attn_fused(const unsigned short* __restrict__ Qg,
                                                  const unsigned short* __restrict__ Kg,
                                                  const unsigned short* __restrict__ Vtg,
                                                  const float* __restrict__ am,
                                                  const float* __restrict__ rel_emb,
                                                  unsigned short* __restrict__ Og,
                                                  float* __restrict__ mout) {
  const int bh = blockIdx.x;           // XCD-affine: all q-tiles of bh on xcd bh%8
  const int b = bh >> 4, h = bh & 15;
  const int q0 = blockIdx.y << 7;
  const int tid = threadIdx.x;
  const int lane = tid & 63, wave = tid >> 6;
  const int l15 = lane & 15, g = lane >> 4;

  __shared__ __align__(16) short Ks[64 * 72];
  __shared__ __align__(16) short Vt[64 * 72];          // Vt[d][j]
  __shared__ unsigned short pbr[2176];                 // bf16 pb, block-local
  __shared__ __align__(16) unsigned short msPl[128 * 72];  // m-tile == P == Qs
  short* Qs = (short*)msPl;

  // pbr[t] = rel_emb[bucket(t - 127 - q0)][h]; idx = j - row_local + 127
  for (int t = tid; t < 2176; t += 512)
    pbr[t] = f2bf(rel_emb[t5_bucket(t - 127 - q0) * 16 + h]);

  const size_t base = ((size_t)b * 2048) * 1024 + h * 64;   // Q/K/O token-major
  const size_t vtbase = (size_t)bh << 17;                   // Vt [bh][64][2048]

  {  // stage Q tile [128][64] -> Qs (aliases msPl; consumed before kt loop)
    int row = tid >> 2, cu = (tid & 3) << 4;
    const unsigned short* src = Qg + base + (size_t)(q0 + row) * 1024 + cu;
    u16x8 v0 = *(const u16x8*)src;
    u16x8 v1 = *(const u16x8*)(src + 8);
    *(u16x8*)(Qs + row * 72 + cu) = v0;
    *(u16x8*)(Qs + row * 72 + cu + 8) = v1;
  }
  __syncthreads();

  bf16x8 qf[2];
  {
    int row = (wave << 4) + l15;
    const short* p = Qs + row * 72 + (g << 3);
    qf[0] = *(const bf16x8*)p;
    qf[1] = *(const bf16x8*)(p + 32);
  }

  f32x4 acc[4] = {};
  f32x4 acc1 = {};                               // P row sums (ones-column)
  const bf16x8 onesf = {16256, 16256, 16256, 16256, 16256, 16256, 16256, 16256};
  const int ilbase = (wave << 4) + (g << 2);     // local q-row for r=0
  const float SC = 1.442695041f / 4096.0f;

  const int srowK = tid >> 3;                    // K/V staging: 64 rows
  const int scuK = (tid & 7) << 3;               // 8 shorts each
  const int mrow = tid >> 4;                     // am staging: 32-row passes
  const int mf4 = tid & 15;                      // float4 index (256B lines)

  for (int kt = 0; kt < 32; ++kt) {
    const int j0 = kt << 6;
    __syncthreads();  // prev readers of Ks/Vt/msPl done; prev stores drained
    {  // stage K and Vt tiles (one u16x8 each per thread)
      const unsigned short* ks = Kg + base + (size_t)(j0 + srowK) * 1024 + scuK;
      *(u16x8*)(Ks + srowK * 72 + scuK) = *(const u16x8*)ks;
      const unsigned short* vs = Vtg + vtbase + ((size_t)srowK << 11) + j0 + scuK;
      *(u16x8*)(Vt + srowK * 72 + scuK) = *(const u16x8*)vs;
    }
    // stage m = pb + am tile (float4 loads, 256B contiguous per 16 lanes)
    f32x4 mreg[4];
#pragma unroll
    for (int p = 0; p < 4; ++p) {
      const int row = p * 32 + mrow;
      const int j = j0 + (mf4 << 2);
      f32x4 a = *(const f32x4*)(am + ((size_t)b * 2048 + q0 + row) * 2048 + j);
      const int pidx = j - row + 127;
      f32x4 m;
      m[0] = bf2f(pbr[pidx + 0]) + a[0];
      m[1] = bf2f(pbr[pidx + 1]) + a[1];
      m[2] = bf2f(pbr[pidx + 2]) + a[2];
      m[3] = bf2f(pbr[pidx + 3]) + a[3];
      mreg[p] = m;
      ushort4 mb;
      mb.x = f2bf(m[0]); mb.y = f2bf(m[1]); mb.z = f2bf(m[2]); mb.w = f2bf(m[3]);
      *(ushort4*)(msPl + row * 72 + (mf4 << 2)) = mb;
    }
    __syncthreads();

    if (WM) {  // nontemporal masks stores; drain overlaps the compute phase
#pragma unroll
      for (int p = 0; p < 4; ++p) {
        const int row = p * 32 + mrow;
        f32x4* dst =
            (f32x4*)(mout + ((size_t)bh * 2048 + q0 + row) * 2048 + j0 + (mf4 << 2));
        __builtin_nontemporal_store(mreg[p], dst);
      }
    }

    // S = Q K^T
    f32x4 sacc[4] = {};
#pragma unroll
    for (int kk = 0; kk < 2; ++kk) {
      const int koff = (kk << 5) + (g << 3);
#pragma unroll
      for (int fj = 0; fj < 4; ++fj) {
        bf16x8 kf = *(const bf16x8*)(Ks + ((fj << 4) + l15) * 72 + koff);
        sacc[fj] = MFMA16(qf[kk], kf, sacc[fj]);
      }
    }

    // P = exp2((s + m) * SC); overwrite m with P in place (same lane+slot)
#pragma unroll
    for (int fj = 0; fj < 4; ++fj) {
      const int jl = (fj << 4) + l15;
#pragma unroll
      for (int r = 0; r < 4; ++r) {
        const int il = (wave << 4) + (g << 2) + r;
        float mval = bf2f(msPl[il * 72 + jl]);
        float p = exp2f((sacc[fj][r] + mval) * SC);
        msPl[il * 72 + jl] = f2bf(p);
      }
    }
    // msPl rows of this wave are wave-private: in-order LDS, no barrier.

    // O += P V ; row sums += P * ones (matrix pipe)
#pragma unroll
    for (int kk = 0; kk < 2; ++kk) {
      const int koff = (kk << 5) + (g << 3);
      bf16x8 pf = *(const bf16x8*)((const short*)msPl + ((wave << 4) + l15) * 72 + koff);
      acc1 = MFMA16(pf, onesf, acc1);
#pragma unroll
      for (int fd = 0; fd < 4; ++fd) {
        bf16x8 vf = *(const bf16x8*)(Vt + ((fd << 4) + l15) * 72 + koff);
        acc[fd] = MFMA16(pf, vf, acc[fd]);
      }
    }
  }

#pragma unroll
  for (int fd = 0; fd < 4; ++fd) {
    int d = (fd << 4) + l15;
#pragma unroll
    for (int r = 0; r < 4; ++r) {
      float o = acc[fd][r] / acc1[r];
      Og[base + (size_t)(q0 + ilbase + r) * 1024 + d] = f2bf(o);
    }
  }
}

// ---------------------------- masks output (fallback path) -----------------
__global__ __launch_bounds__(256) void masks_kernel(const float* __restrict__ am,
                                                    const float* __restrict__ rel_emb,
                                                    float* __restrict__ mout) {
  const int bi = blockIdx.x;
  const int b = bi >> 11, i = bi & 2047;
  __shared__ float amrow[2048];
  __shared__ float remb[512];
  __shared__ unsigned char bkt[2048];
  for (int t = threadIdx.x; t < 512; t += 256) remb[t] = rel_emb[t];
  const float* arow = am + ((size_t)b * 2048 + i) * 2048;
  for (int t = threadIdx.x; t < 512; t += 256)
    *(float4*)(amrow + (t << 2)) = *(const float4*)(arow + (t << 2));
  for (int j = threadIdx.x; j < 2048; j += 256)
    bkt[j] = (unsigned char)t5_bucket(j - i);
  __syncthreads();
  for (int h = 0; h < 16; ++h) {
    float* dst = mout + (((size_t)(b * 16 + h)) * 2048 + i) * 2048;
    for (int t = threadIdx.x; t < 512; t += 256) {
      int j = t << 2;
      f32x4 o;
      o[0] = remb[(bkt[j + 0] << 4) + h] + amrow[j + 0];
      o[1] = remb[(bkt[j + 1] << 4) + h] + amrow[j + 1];
      o[2] = remb[(bkt[j + 2] << 4) + h] + amrow[j + 2];
      o[3] = remb[(bkt[j + 3] << 4) + h] + amrow[j + 3];
      __builtin_nontemporal_store(o, (f32x4*)(dst + j));
    }
  }
}

// ---------------------------------------------------------------------------
extern "C" void kernel_launch(void* const* d_in, const int* in_sizes, int n_in,
                              void* d_out, int out_size, void* d_ws, size_t ws_size,
                              hipStream_t stream) {
  const float* hs  = (const float*)d_in[0];
  const float* am  = (const float*)d_in[1];
  const float* Wq  = (const float*)d_in[2];
  const float* bq  = (const float*)d_in[3];
  const float* Wk  = (const float*)d_in[4];
  const float* bk  = (const float*)d_in[5];
  const float* Wv  = (const float*)d_in[6];
  const float* bv  = (const float*)d_in[7];
  const float* Wo  = (const float*)d_in[8];
  const float* bo  = (const float*)d_in[9];
  const float* rel = (const float*)d_in[10];

  float* out = (float*)d_out;
  float* mout = out + (size_t)8388608;           // masks region (1.07 GB)

  const bool fused = ws_size >= (size_t)69206016;

  unsigned short *hsb, *wqb, *wkb, *wvb, *wob, *qb, *kb, *vtb, *aob;
  if (fused) {
    char* W = (char*)d_ws;
    qb  = (unsigned short*)(W);
    kb  = (unsigned short*)(W + 16777216);
    vtb = (unsigned short*)(W + 33554432);
    aob = (unsigned short*)(W + 50331648);
    wob = (unsigned short*)(W + 67108864);
    char* SB = (char*)mout;
    hsb = (unsigned short*)(SB);
    wqb = (unsigned short*)(SB + 16777216);
    wkb = (unsigned short*)(SB + 18874368);
    wvb = (unsigned short*)(SB + 20971520);
  } else {
    char* SB = (char*)mout;
    hsb = (unsigned short*)(SB);
    wqb = (unsigned short*)(SB + 16777216);
    wkb = (unsigned short*)(SB + 18874368);
    wvb = (unsigned short*)(SB + 20971520);
    wob = (unsigned short*)(SB + 23068672);
    qb  = (unsigned short*)(SB + 25165824);
    kb  = (unsigned short*)(SB + 41943040);
    vtb = (unsigned short*)(SB + 58720256);
    aob = (unsigned short*)(SB + 75497472);
  }

  Cast5Args ca;
  ca.src[0] = hs;  ca.dst[0] = hsb;
  ca.src[1] = Wq;  ca.dst[1] = wqb;
  ca.src[2] = Wk;  ca.dst[2] = wkb;
  ca.src[3] = Wv;  ca.dst[3] = wvb;
  ca.src[4] = Wo;  ca.dst[4] = wob;
  cast5_kernel<<<12288, 256, 0, stream>>>(ca);

  QKVArgs qa;
  qa.A = hsb;
  qa.Bt[0] = wqb;  qa.bias[0] = bq;  qa.out[0] = qb;
  qa.Bt[1] = wkb;  qa.bias[1] = bk;  qa.out[1] = kb;
  qa.Bt[2] = wvb;  qa.bias[2] = bv;  qa.out[2] = vtb;
  qkv_gemm<<<dim3(64, 8, 3), 256, 0, stream>>>(qa);

  if (fused) {
    attn_fused<1><<<dim3(64, 16), 512, 0, stream>>>(qb, kb, vtb, am, rel, aob, mout);
  } else {
    attn_fused<0><<<dim3(64, 16), 512, 0, stream>>>(qb, kb, vtb, am, rel, aob, mout);
  }

  gemm_f32<<<dim3(64, 8), 256, 0, stream>>>(aob, wob, bo, out);

  if (!fused) masks_kernel<<<8192, 256, 0, stream>>>(am, rel, mout);
}